// Round 1
// baseline (1614.920 us; speedup 1.0000x reference)
//
#include <hip/hip_runtime.h>
#include <math.h>

// Problem constants (fixed by the reference)
#define TOKENS 32768
#define HDIM   4096
#define NEXP   128
#define TOPK   8

// Tiling: 64 tokens per block, H chunk of 64.
// Thread mapping (256 threads): tx = t&15 -> experts [tx*8, tx*8+8),
//                               ty = t>>4 -> tokens  [4*ty, 4*ty+4)
// => 4x8 fp64 accumulators per thread.
#define BT 64
#define BH 64
#define AS_STRIDE 68   // 64 + 4 pad: row offset 272 B (16B-aligned), breaks bank aliasing
#define WS_STRIDE 132  // 128 + 4 pad: row offset 528 B (16B-aligned)

__global__ __launch_bounds__(256, 2)
void glm4v_router_kernel(const float* __restrict__ hs,
                         const float* __restrict__ wt,
                         const float* __restrict__ bias,
                         float* __restrict__ out)
{
    __shared__ float As[BH * AS_STRIDE];   // [h][token] transposed tile, 17.4 KB
    __shared__ float Ws[BH * WS_STRIDE];   // [h][expert] transposed tile, 33.8 KB
    __shared__ float bias_s[NEXP];

    const int t  = threadIdx.x;
    const int tx = t & 15;   // expert group
    const int ty = t >> 4;   // token group
    const int tokBase = blockIdx.x * BT;

    if (t < NEXP) bias_s[t] = bias[t];

    double acc[4][8];
    #pragma unroll
    for (int i = 0; i < 4; ++i)
        #pragma unroll
        for (int k = 0; k < 8; ++k) acc[i][k] = 0.0;

    // staging roles: col4 = float4 column (0..15), rowq = row quarter (0..15)
    const int col4 = t & 15;
    const int rowq = t >> 4;

    for (int hc = 0; hc < HDIM; hc += BH) {
        __syncthreads();   // protect LDS from previous chunk's compute readers

        // Stage A tile: 64 tokens x 64 floats, coalesced float4 reads along H,
        // transposed scalar writes into As[h][token].
        #pragma unroll
        for (int j = 0; j < 4; ++j) {
            const int row = rowq + 16 * j;
            const float4 v = *(const float4*)(hs + (size_t)(tokBase + row) * HDIM + hc + col4 * 4);
            const int h = col4 * 4;
            As[(h + 0) * AS_STRIDE + row] = v.x;
            As[(h + 1) * AS_STRIDE + row] = v.y;
            As[(h + 2) * AS_STRIDE + row] = v.z;
            As[(h + 3) * AS_STRIDE + row] = v.w;
        }
        // Stage W tile: 128 experts x 64 floats.
        #pragma unroll
        for (int j = 0; j < 8; ++j) {
            const int e = rowq + 16 * j;
            const float4 v = *(const float4*)(wt + (size_t)e * HDIM + hc + col4 * 4);
            const int h = col4 * 4;
            Ws[(h + 0) * WS_STRIDE + e] = v.x;
            Ws[(h + 1) * WS_STRIDE + e] = v.y;
            Ws[(h + 2) * WS_STRIDE + e] = v.z;
            Ws[(h + 3) * WS_STRIDE + e] = v.w;
        }
        __syncthreads();

        // fp64 accumulation: exact fp32->fp64 convert, one rounding per FMA.
        #pragma unroll 4
        for (int h = 0; h < BH; ++h) {
            const float4 av = *(const float4*)(As + h * AS_STRIDE + 4 * ty);
            const float4 w0 = *(const float4*)(Ws + h * WS_STRIDE + tx * 8);
            const float4 w1 = *(const float4*)(Ws + h * WS_STRIDE + tx * 8 + 4);
            const double a[4] = { (double)av.x, (double)av.y, (double)av.z, (double)av.w };
            const double w[8] = { (double)w0.x, (double)w0.y, (double)w0.z, (double)w0.w,
                                  (double)w1.x, (double)w1.y, (double)w1.z, (double)w1.w };
            #pragma unroll
            for (int i = 0; i < 4; ++i)
                #pragma unroll
                for (int k = 0; k < 8; ++k)
                    acc[i][k] = fma(a[i], w[k], acc[i][k]);
        }
    }
    __syncthreads();

    // ---- Top-8 per token. Token (4*ty+i)'s 128 experts live in the 16 lanes
    // sharing ty (one aligned 16-lane group of a wave), 8 experts each.
    const int lane = t & 63;
    const int grpBase = lane & 48;   // first lane of this 16-lane group

    for (int i = 0; i < 4; ++i) {
        const int tok = tokBase + 4 * ty + i;

        double ss[8];   // sigmoid (the weight value)
        double rr[8];   // ranking value = sigmoid + bias
        #pragma unroll
        for (int k = 0; k < 8; ++k) {
            const double x = acc[i][k];
            const double s = 1.0 / (1.0 + exp(-x));
            ss[k] = s;
            rr[k] = s + (double)bias_s[tx * 8 + k];
        }

        int    sel[TOPK];
        double wv[TOPK];
        #pragma unroll
        for (int r = 0; r < TOPK; ++r) {
            // local max over 8 (strict > keeps lowest expert index on ties)
            double bv = rr[0]; int bi = tx * 8;
            #pragma unroll
            for (int k = 1; k < 8; ++k)
                if (rr[k] > bv) { bv = rr[k]; bi = tx * 8 + k; }
            // 16-lane butterfly; stable tie-break: lower index wins
            #pragma unroll
            for (int m = 1; m <= 8; m <<= 1) {
                const double ov = __shfl_xor(bv, m, 64);
                const int    oi = __shfl_xor(bi, m, 64);
                if (ov > bv || (ov == bv && oi < bi)) { bv = ov; bi = oi; }
            }
            sel[r] = bi;
            // fetch the winner's exact sigmoid from its owner lane
            double sv = 0.0;
            #pragma unroll
            for (int k = 0; k < 8; ++k)
                if (k == (bi & 7)) sv = ss[k];
            wv[r] = __shfl(sv, grpBase | (bi >> 3), 64);
            // mask the winner on its owner lane (static-indexed to stay in regs)
            if ((bi >> 3) == tx) {
                #pragma unroll
                for (int k = 0; k < 8; ++k)
                    if (k == (bi & 7)) rr[k] = -INFINITY;
            }
        }

        if (tx == 0) {
            double denom = 1e-20;
            #pragma unroll
            for (int r = 0; r < TOPK; ++r) denom += wv[r];
            #pragma unroll
            for (int r = 0; r < TOPK; ++r) {
                out[(size_t)tok * TOPK + r] = (float)sel[r];   // indices half (as float)
                out[(size_t)TOKENS * TOPK + (size_t)tok * TOPK + r] = (float)(wv[r] / denom);
            }
        }
    }
}

extern "C" void kernel_launch(void* const* d_in, const int* in_sizes, int n_in,
                              void* d_out, int out_size, void* d_ws, size_t ws_size,
                              hipStream_t stream) {
    const float* hs   = (const float*)d_in[0];   // [32768, 4096] fp32
    const float* wt   = (const float*)d_in[1];   // [128, 4096] fp32
    const float* bias = (const float*)d_in[2];   // [128] fp32
    float* out = (float*)d_out;                  // [T*8] indices-as-float, then [T*8] weights

    dim3 grid(TOKENS / BT);   // 512 blocks
    dim3 block(256);
    glm4v_router_kernel<<<grid, block, 0, stream>>>(hs, wt, bias, out);
}

// Round 3
// 1341.923 us; speedup vs baseline: 1.2034x; 1.2034x over previous
//
#include <hip/hip_runtime.h>
#include <math.h>

// Glm4vMoeTextTopkRouter: logits = hs[32768,4096] @ wt[128,4096]^T in fp64 via
// v_mfma_f64_16x16x4_f64 (matrix pipe), then sigmoid/+bias/top-8 intra-wave.
// fp64 needed: index outputs compared exactly; fp32 accumulation flips ranks.
// The f64 MFMA C/D layout is NOT among the HW-verified cells, so this version
// self-calibrates the D row/col mapping with two constant MFMAs (R2 failed
// with what looks like a row-relabeling error).
#define TOKENS 32768
#define HDIM   4096
#define NEXP   128
#define TOPK   8
#define BT     64    // tokens per block (4 waves x 16)
#define BH     64    // K-chunk
#define LSTR   68    // LDS row stride (+4 pad: 272 B rows, 16B-aligned, bank scatter)

typedef __attribute__((ext_vector_type(4))) double dbl4;

__global__ __launch_bounds__(256, 2)
void glm4v_router_mfma(const float* __restrict__ hs,
                       const float* __restrict__ wt,
                       const float* __restrict__ bias,
                       float* __restrict__ out)
{
    __shared__ float As[BT * LSTR];     // [token][k], global layout copy
    __shared__ float Ws[NEXP * LSTR];   // [expert][k], global layout copy
    __shared__ float bias_s[NEXP];

    const int t    = threadIdx.x;
    const int w    = t >> 6;       // wave 0..3 -> tokens [w*16, w*16+16)
    const int lane = t & 63;
    const int col  = lane & 15;    // fed as: A token-row / B expert-col
    const int q    = lane >> 4;    // fed as: MFMA k-slot

    const int tokBase = blockIdx.x * BT;

    if (t < NEXP) bias_s[t] = bias[t];

    dbl4 acc[8];
    #pragma unroll
    for (int et = 0; et < 8; ++et) acc[et] = (dbl4){0.0, 0.0, 0.0, 0.0};

    // staging roles: sr = row 0..15, sc = float4 column offset (floats)
    const int sr = t >> 4;
    const int sc = (t & 15) * 4;

    const float* __restrict__ aRow = As + (w * 16 + col) * LSTR + q * 4;

    for (int hc = 0; hc < HDIM; hc += BH) {
        __syncthreads();   // previous chunk's readers done (also makes bias_s visible)
        // A tile: 64 rows x 64 floats (coalesced 256 B per 16-lane group)
        #pragma unroll
        for (int j = 0; j < 4; ++j) {
            const int row = sr + 16 * j;
            const float4 v = *(const float4*)(hs + (size_t)(tokBase + row) * HDIM + hc + sc);
            *(float4*)(As + row * LSTR + sc) = v;
        }
        // W tile: 128 rows x 64 floats
        #pragma unroll
        for (int j = 0; j < 8; ++j) {
            const int e = sr + 16 * j;
            const float4 v = *(const float4*)(wt + (size_t)e * HDIM + hc + sc);
            *(float4*)(Ws + e * LSTR + sc) = v;
        }
        __syncthreads();

        // K-permutation trick: lane quarter q supplies logical k = kb + 4q + s
        // in MFMA #s; A and B agree on (q,s), so fragments are contiguous
        // float4 -> ds_read_b128, no transpose needed.
        #pragma unroll
        for (int kb = 0; kb < BH; kb += 16) {
            const float4 a4 = *(const float4*)(aRow + kb);
            float4 b4[8];
            #pragma unroll
            for (int et = 0; et < 8; ++et)
                b4[et] = *(const float4*)(Ws + (et * 16 + col) * LSTR + kb + q * 4);
            const float* ap = (const float*)&a4;
            #pragma unroll
            for (int s = 0; s < 4; ++s) {
                const double ad = (double)ap[s];
                #pragma unroll
                for (int et = 0; et < 8; ++et) {
                    const double bd = (double)((const float*)&b4[et])[s];
                    acc[et] = __builtin_amdgcn_mfma_f64_16x16x4f64(ad, bd, acc[et], 0, 0, 0);
                }
            }
        }
    }

    // ---- D-layout calibration (2 constant MFMAs). With A[m][k] fed as m for
    // all k and B = 0.25: D[m][n] = m. With A = 0.25, B[k][n] = n: D[m][n] = n.
    // So rowcal[j]/colcal[j] tell this lane which (row, col) its acc slot j
    // holds, under whatever permutation the HW actually uses.
    dbl4 rowcal = (dbl4){0.0, 0.0, 0.0, 0.0};
    dbl4 colcal = (dbl4){0.0, 0.0, 0.0, 0.0};
    const double dcol = (double)col;
    rowcal = __builtin_amdgcn_mfma_f64_16x16x4f64(dcol, 0.25, rowcal, 0, 0, 0);
    colcal = __builtin_amdgcn_mfma_f64_16x16x4f64(0.25, dcol, colcal, 0, 0, 0);

    // ---- Epilogue (intra-wave). A token's 16 expert-holding lanes are the
    // 16-lane shuffle group sharing lane>>4 (rows depend only on (q, reg) in
    // every CDNA 16x16 D variant); labels come from the calibration.
    #pragma unroll
    for (int j = 0; j < 4; ++j) {
        const int rj = (int)(rowcal[j] + 0.5);   // token row in wave tile (0..15)
        const int cj = (int)(colcal[j] + 0.5);   // expert low index (0..15)
        const int tok = tokBase + w * 16 + rj;

        double ss[8];   // sigmoid (weight value)
        double rr[8];   // ranking value = sigmoid + bias
        #pragma unroll
        for (int et = 0; et < 8; ++et) {
            const double x = acc[et][j];
            const double s = 1.0 / (1.0 + exp(-x));
            ss[et] = s;
            rr[et] = s + (double)bias_s[et * 16 + cj];
        }

        int    sel[TOPK];
        double wv[TOPK];
        #pragma unroll
        for (int r = 0; r < TOPK; ++r) {
            // local max over 8 (strict > keeps lowest expert index; experts
            // et*16+cj ascend with et for fixed lane)
            double bv = rr[0]; int bi = cj; int bl = lane;
            #pragma unroll
            for (int et = 1; et < 8; ++et)
                if (rr[et] > bv) { bv = rr[et]; bi = et * 16 + cj; }
            // 16-lane butterfly carrying (value, expert, owner-lane);
            // stable tie-break: lower expert index wins
            #pragma unroll
            for (int m = 1; m <= 8; m <<= 1) {
                const double ov = __shfl_xor(bv, m, 64);
                const int    oi = __shfl_xor(bi, m, 64);
                const int    ol = __shfl_xor(bl, m, 64);
                if (ov > bv || (ov == bv && oi < bi)) { bv = ov; bi = oi; bl = ol; }
            }
            sel[r] = bi;
            // winner's exact sigmoid from its owner lane (static-index select)
            double sv = ss[0];
            #pragma unroll
            for (int et = 1; et < 8; ++et)
                if ((bi >> 4) == et) sv = ss[et];
            wv[r] = __shfl(sv, bl, 64);
            // mask winner on owner lane
            if (bl == lane) {
                #pragma unroll
                for (int et = 0; et < 8; ++et)
                    if ((bi >> 4) == et) rr[et] = -INFINITY;
            }
        }

        if (cj == 0) {   // exactly one lane per 16-lane group
            double denom = 1e-20;
            #pragma unroll
            for (int r = 0; r < TOPK; ++r) denom += wv[r];
            #pragma unroll
            for (int r = 0; r < TOPK; ++r) {
                out[(size_t)tok * TOPK + r] = (float)sel[r];   // indices half (as float)
                out[(size_t)TOKENS * TOPK + (size_t)tok * TOPK + r] = (float)(wv[r] / denom);
            }
        }
    }
}

extern "C" void kernel_launch(void* const* d_in, const int* in_sizes, int n_in,
                              void* d_out, int out_size, void* d_ws, size_t ws_size,
                              hipStream_t stream) {
    const float* hs   = (const float*)d_in[0];   // [32768, 4096] fp32
    const float* wt   = (const float*)d_in[1];   // [128, 4096] fp32
    const float* bias = (const float*)d_in[2];   // [128] fp32
    float* out = (float*)d_out;                  // [T*8] indices-as-float, then [T*8] weights

    dim3 grid(TOKENS / BT);   // 512 blocks, 2 per CU
    dim3 block(256);
    glm4v_router_mfma<<<grid, block, 0, stream>>>(hs, wt, bias, out);
}